// Round 1
// baseline (38.515 us; speedup 1.0000x reference)
//
#include <hip/hip_runtime.h>

#define MAXLEN 4096
#define NB 16
#define NT 512
#define ND 384
#define ND4 96   // D / 4 float4 per frame

// Kernel A: per-batch n = max(1, rint(dur)); inclusive scan; cum -> ws;
// lengths (as float) -> tail of d_out.
__global__ __launch_bounds__(NT) void lr_scan_kernel(
    const float* __restrict__ dur, int* __restrict__ cum,
    float* __restrict__ len_out) {
  __shared__ int s[NT];
  const int b = blockIdx.x;
  const int t = threadIdx.x;
  float d = dur[b * NT + t];
  int n = (int)rintf(d);   // RTE matches jnp.round (half-to-even)
  if (n < 1) n = 1;
  s[t] = n;
  __syncthreads();
  // Hillis-Steele inclusive scan over 512 elements
  for (int off = 1; off < NT; off <<= 1) {
    int v = (t >= off) ? s[t - off] : 0;
    __syncthreads();
    s[t] += v;
    __syncthreads();
  }
  cum[b * NT + t] = s[t];
  if (t == NT - 1) len_out[b] = (float)s[t];
}

// Kernel B: each block handles 4 frames (4 x 96 float4 = 384 threads).
// Threads 0..3 binary-search the token index for their frame; all threads
// then do a coalesced float4 gather/store (zero past lengths[b]).
__global__ __launch_bounds__(384) void lr_gather_kernel(
    const float4* __restrict__ enc, const int* __restrict__ cum,
    float4* __restrict__ out) {
  __shared__ int sidx[4];
  const int fbase = blockIdx.x * 4;     // global frame index base
  const int lf = threadIdx.x / ND4;     // 0..3 local frame
  const int d4 = threadIdx.x % ND4;     // 0..95 float4 within frame

  if (threadIdx.x < 4) {
    const int fg = fbase + threadIdx.x;
    const int b = fg >> 12;             // MAXLEN = 4096
    const int f = fg & (MAXLEN - 1);
    const int* c = cum + b * NT;
    const int len = c[NT - 1];
    int idx = -1;
    if (f < len) {
      // upper_bound: first j with c[j] > f  (== searchsorted side='right')
      int lo = 0, hi = NT;
      while (lo < hi) {
        int mid = (lo + hi) >> 1;
        if (c[mid] <= f) lo = mid + 1; else hi = mid;
      }
      idx = (lo < NT) ? lo : NT - 1;    // min(idx, T-1); f<len implies lo<NT
    }
    sidx[threadIdx.x] = idx;
  }
  __syncthreads();

  const int fg = fbase + lf;
  const int b = fg >> 12;
  const int idx = sidx[lf];
  float4 v = make_float4(0.f, 0.f, 0.f, 0.f);
  if (idx >= 0) v = enc[((size_t)(b * NT + idx)) * ND4 + d4];
  out[(size_t)fg * ND4 + d4] = v;
}

extern "C" void kernel_launch(void* const* d_in, const int* in_sizes, int n_in,
                              void* d_out, int out_size, void* d_ws, size_t ws_size,
                              hipStream_t stream) {
  const float* enc = (const float*)d_in[0];       // [16,512,384] f32
  const float* dur = (const float*)d_in[1];       // [16,512] f32
  float* out_f = (float*)d_out;                   // [16*4096*384] + [16]
  int* cum = (int*)d_ws;                          // 16*512 int32 = 32 KB

  float* len_out = out_f + (size_t)NB * MAXLEN * ND;

  lr_scan_kernel<<<NB, NT, 0, stream>>>(dur, cum, len_out);
  lr_gather_kernel<<<(NB * MAXLEN) / 4, 384, 0, stream>>>(
      (const float4*)enc, cum, (float4*)d_out);
}

// Round 2
// 28.451 us; speedup vs baseline: 1.3537x; 1.3537x over previous
//
#include <hip/hip_runtime.h>

#define MAXLEN 4096
#define NB 16
#define NT 512
#define ND 384
#define ND4 96   // D/4 float4 per frame

#define GB_BLOCKS 2048
#define GB_THREADS 256
#define GB_TOTAL (NB * MAXLEN * ND4)                     // 6,291,456 float4
#define GB_ITERS (GB_TOTAL / (GB_BLOCKS * GB_THREADS))   // 12 exactly

// Kernel A: n = max(1, rint(dur)); inclusive scan in LDS; then each thread
// SCATTERS its token index t into the per-frame index array for frames
// [cum[t]-n, cum[t]) and cooperatively fills the tail [len, MAXLEN) with -1.
// No binary search anywhere. Also writes lengths (as float) to d_out tail.
__global__ __launch_bounds__(NT) void lr_scan_idx_kernel(
    const float* __restrict__ dur, int* __restrict__ sidx,
    float* __restrict__ len_out) {
  __shared__ int s[NT];
  const int b = blockIdx.x;
  const int t = threadIdx.x;
  int n = (int)rintf(dur[b * NT + t]);  // RTE == jnp.round half-to-even
  if (n < 1) n = 1;
  s[t] = n;
  __syncthreads();
  // Hillis-Steele inclusive scan over 512 elements
  for (int off = 1; off < NT; off <<= 1) {
    int v = (t >= off) ? s[t - off] : 0;
    __syncthreads();
    s[t] += v;
    __syncthreads();
  }
  int end = s[t];
  const int start = end - n;
  const int len = s[NT - 1];

  int* row = sidx + b * MAXLEN;
  if (end > MAXLEN) end = MAXLEN;
  for (int j = start; j < end; ++j) row[j] = t;   // repeat token t
  for (int j = len + t; j < MAXLEN; j += NT) row[j] = -1;  // zero region
  if (t == NT - 1) len_out[b] = (float)len;
}

// Kernel B: pure streaming gather. i indexes float4 elements of the output
// tensor. frame = i/96; idx = sidx[frame]; copy enc row float4 or zero.
// Exactly GB_ITERS iterations per thread, unrolled for ILP — no LDS, no sync.
__global__ __launch_bounds__(GB_THREADS) void lr_gather_kernel(
    const float4* __restrict__ enc, const int* __restrict__ sidx,
    float4* __restrict__ out) {
  int i = blockIdx.x * GB_THREADS + threadIdx.x;
  const int stride = GB_BLOCKS * GB_THREADS;
#pragma unroll
  for (int k = 0; k < GB_ITERS; ++k) {
    const int frame = i / ND4;          // magic-mul, cheap
    const int d4 = i - frame * ND4;
    const int b = frame >> 12;          // MAXLEN = 4096
    const int idx = sidx[frame];
    float4 v = make_float4(0.f, 0.f, 0.f, 0.f);
    if (idx >= 0) v = enc[(size_t)((b << 9) + idx) * ND4 + d4];
    out[i] = v;
    i += stride;
  }
}

extern "C" void kernel_launch(void* const* d_in, const int* in_sizes, int n_in,
                              void* d_out, int out_size, void* d_ws, size_t ws_size,
                              hipStream_t stream) {
  const float* enc = (const float*)d_in[0];   // [16,512,384] f32
  const float* dur = (const float*)d_in[1];   // [16,512] f32
  float* out_f = (float*)d_out;               // [16*4096*384] + [16]
  int* sidx = (int*)d_ws;                     // 16*4096 int32 = 256 KB

  float* len_out = out_f + (size_t)NB * MAXLEN * ND;

  lr_scan_idx_kernel<<<NB, NT, 0, stream>>>(dur, sidx, len_out);
  lr_gather_kernel<<<GB_BLOCKS, GB_THREADS, 0, stream>>>(
      (const float4*)enc, sidx, (float4*)d_out);
}

// Round 3
// 22.770 us; speedup vs baseline: 1.6915x; 1.2495x over previous
//
#include <hip/hip_runtime.h>

#define MAXLEN 4096
#define NB 16
#define NT 512     // tokens per batch == threads per block
#define ND 384
#define ND4 96     // D/4 float4 per frame

#define FCHUNK 128                         // frames per block
#define NCHUNK (MAXLEN / FCHUNK)           // 32 chunks per batch
#define ELEMS (FCHUNK * ND4)               // 12288 float4 per block
#define GITER (ELEMS / NT)                 // 24 gather iterations per thread

// One fused kernel. Each block: redundantly scan its batch's 512 durations
// (2 KB, L2-hit), scatter token ids for its 128-frame chunk into LDS (each
// thread owns frames [cum-n, cum) — no search), then stream the chunk:
// coalesced float4 gather from enc, store to out, zero past length.
__global__ __launch_bounds__(NT) void lr_fused_kernel(
    const float* __restrict__ dur, const float4* __restrict__ enc,
    float4* __restrict__ out, float* __restrict__ len_out) {
  __shared__ int s[NT];
  __shared__ int sidx[FCHUNK];

  const int b = blockIdx.y;
  const int f0 = blockIdx.x * FCHUNK;
  const int t = threadIdx.x;

  int n = (int)rintf(dur[b * NT + t]);  // RTE == jnp.round half-to-even
  if (n < 1) n = 1;
  s[t] = n;
  __syncthreads();
  // Hillis-Steele inclusive scan over 512
  for (int off = 1; off < NT; off <<= 1) {
    int v = (t >= off) ? s[t - off] : 0;
    __syncthreads();
    s[t] += v;
    __syncthreads();
  }
  const int end = s[t];
  const int start = end - n;
  const int len = s[NT - 1];

  // default -1 (zero-fill region: frames >= len)
  if (t < FCHUNK) sidx[t] = (f0 + t < len) ? 0 : -1;
  __syncthreads();
  // scatter: this thread's frames intersected with [f0, f0+FCHUNK)
  {
    int lo = start > f0 ? start : f0;
    int hi = end < f0 + FCHUNK ? end : f0 + FCHUNK;
    for (int j = lo; j < hi; ++j) sidx[j - f0] = t;
  }
  if (blockIdx.x == 0 && t == 0) len_out[b] = (float)len;
  __syncthreads();

  // streaming gather/store for this chunk
  const float4* encb = enc + (size_t)b * NT * ND4;
  float4* outb = out + ((size_t)b * MAXLEN + f0) * ND4;
#pragma unroll
  for (int k = 0; k < GITER; ++k) {
    const int j = t + k * NT;           // 0..12287
    const int lf = j / ND4;
    const int d4 = j - lf * ND4;
    const int idx = sidx[lf];
    float4 v = make_float4(0.f, 0.f, 0.f, 0.f);
    if (idx >= 0) v = encb[idx * ND4 + d4];
    outb[j] = v;
  }
}

extern "C" void kernel_launch(void* const* d_in, const int* in_sizes, int n_in,
                              void* d_out, int out_size, void* d_ws, size_t ws_size,
                              hipStream_t stream) {
  const float* enc = (const float*)d_in[0];   // [16,512,384] f32
  const float* dur = (const float*)d_in[1];   // [16,512] f32
  float* out_f = (float*)d_out;               // [16*4096*384] + [16]
  float* len_out = out_f + (size_t)NB * MAXLEN * ND;

  dim3 grid(NCHUNK, NB);
  lr_fused_kernel<<<grid, NT, 0, stream>>>(
      dur, (const float4*)enc, (float4*)d_out, len_out);
}